// Round 3
// baseline (88.472 us; speedup 1.0000x reference)
//
#include <hip/hip_runtime.h>

#define NN 177
#define NEG 0.2f
#define EB 64        // edge blocks (each owns a full private W in LDS)
#define ET 1024      // edge threads per block
#define WCELLS 31329 // 177*177
#define SLICE 31552  // per-block partial slice: [W 0..31329) pad [wlast 31360..31537) pad
#define WLAST_IN_SLICE 31360
// workspace layout (floats):
#define AI_OFF   31552
#define AJ_OFF   31744
#define G_OFF    31936
#define PART_OFF 54592  // EB slices of SLICE floats (~8.1 MB); final W/wlast reduced into [0, SLICE)

// K1: h = x@weight (row in LDS); ai/aj attention dots; G = h@eu.
__global__ void k_node(const float* __restrict__ x, const float* __restrict__ w,
                       const float* __restrict__ att, const float* __restrict__ eu,
                       float* __restrict__ ws) {
    int n = blockIdx.x, c = threadIdx.x;
    __shared__ float xl[128], hl[128], r0[128], r1[128];
    xl[c] = x[n * 128 + c];
    __syncthreads();
    float acc = 0.f;
#pragma unroll 8
    for (int k = 0; k < 128; ++k) acc += xl[k] * w[k * 128 + c];
    hl[c] = acc;
    r0[c] = acc * att[c];
    r1[c] = acc * att[128 + c];
    __syncthreads();
    for (int off = 64; off > 0; off >>= 1) {
        if (c < off) { r0[c] += r0[c + off]; r1[c] += r1[c + off]; }
        __syncthreads();
    }
    if (c == 0) { ws[AI_OFF + n] = r0[0]; ws[AJ_OFF + n] = r1[0]; }
    __syncthreads();
    float acc2 = 0.f;
#pragma unroll 8
    for (int k = 0; k < 128; ++k) acc2 += hl[k] * eu[k * 128 + c];
    ws[G_OFF + n * 128 + c] = acc2;
}

// K2: single edge pass, private W accumulator in LDS, coalesced partial flush.
__global__ void k_edge(const int* __restrict__ ei, const float* __restrict__ ea,
                       const float* __restrict__ att, float* __restrict__ ws, int E) {
    extern __shared__ float Wl[];                 // WCELLS floats (125 KB)
    __shared__ float ail[NN], ajl[NN], Ml[NN], llast[NN];
    int tid = threadIdx.x;
    for (int i = tid; i < WCELLS; i += ET) Wl[i] = 0.f;
    for (int i = tid; i < NN; i += ET) {
        ail[i] = ws[AI_OFF + i];
        ajl[i] = ws[AJ_OFF + i];
        llast[i] = 0.f;
    }
    float cc = att[2 * 128];
    __syncthreads();
    // per-dst safe softmax shift: M_d = leaky(ai[d] + max_s aj[s] + 0.6)
    float ajmax = -1e30f;
    for (int i = 0; i < NN; ++i) ajmax = fmaxf(ajmax, ajl[i]);
    float mb = ajmax + 0.6f;
    for (int i = tid; i < NN; i += ET) {
        float M = ail[i] + mb;
        Ml[i] = (M > 0.f) ? M : NEG * M;
    }
    __syncthreads();

    int stride = gridDim.x * blockDim.x;
    for (int e = blockIdx.x * blockDim.x + tid; e < E; e += stride) {
        int s = ei[e];
        int d = ei[E + e];
        float eav = ea[e];
        float t = ail[d] + ajl[s] + cc * eav;
        t = (t > 0.f) ? t : NEG * t;              // leaky
        float ev = __expf(t - Ml[d]);
        atomicAdd(&Wl[d * NN + s], ev);           // LDS fp atomic (ds_add_f32)
        atomicAdd(&llast[d], ev * eav);           // LDS
    }
    __syncthreads();
    // coalesced flush of this block's slice (plain stores, no atomics)
    float* part = ws + PART_OFF + (size_t)blockIdx.x * SLICE;
    for (int i = tid; i < SLICE; i += ET) {
        float v = 0.f;
        if (i < WCELLS) v = Wl[i];
        else if (i >= WLAST_IN_SLICE && i < WLAST_IN_SLICE + NN) v = llast[i - WLAST_IN_SLICE];
        part[i] = v;
    }
}

// K3: reduce EB partial slices -> final slice at ws[0, SLICE)
__global__ void k_reduce(float* __restrict__ ws) {
    int idx = blockIdx.x * 256 + threadIdx.x;
    if (idx >= SLICE) return;
    const float* part = ws + PART_OFF;
    float acc = 0.f;
#pragma unroll 8
    for (int b = 0; b < EB; ++b) acc += part[(size_t)b * SLICE + idx];
    ws[idx] = acc;
}

// K4: out[n][c] = (W[n,:]@G[:,c] + wlast[n]*eu[128,c]) / (sum(W[n,:])+1e-16) + bias[c]
__global__ void k_out(const float* __restrict__ ws, const float* __restrict__ eu,
                      const float* __restrict__ bias, float* __restrict__ out) {
    int n = blockIdx.x, c = threadIdx.x;
    __shared__ float wl[NN];
    for (int i = c; i < NN; i += 128) wl[i] = ws[n * NN + i];
    __syncthreads();
    float ssum = 0.f;
    for (int s = 0; s < NN; ++s) ssum += wl[s];
    const float* G = ws + G_OFF;
    float acc = 0.f;
#pragma unroll 4
    for (int s = 0; s < NN; ++s) acc += wl[s] * G[s * 128 + c];
    float denom = ssum + 1e-16f;
    out[n * 128 + c] = (acc + ws[WLAST_IN_SLICE + n] * eu[128 * 128 + c]) / denom + bias[c];
}

extern "C" void kernel_launch(void* const* d_in, const int* in_sizes, int n_in,
                              void* d_out, int out_size, void* d_ws, size_t ws_size,
                              hipStream_t stream) {
    const float* x     = (const float*)d_in[0];
    const float* eattr = (const float*)d_in[1];
    const float* w     = (const float*)d_in[2];
    const float* att   = (const float*)d_in[3];
    const float* eu    = (const float*)d_in[4];
    const float* bias  = (const float*)d_in[5];
    const int*   ei    = (const int*)d_in[6];
    int E = in_sizes[6] / 2;
    float* ws = (float*)d_ws;

    // allow 125 KB dynamic LDS for k_edge (host-side, capture-safe)
    static bool attr_set = false;
    if (!attr_set) {
        hipFuncSetAttribute((const void*)k_edge,
                            hipFuncAttributeMaxDynamicSharedMemorySize, WCELLS * 4);
        attr_set = true;
    }

    k_node<<<NN, 128, 0, stream>>>(x, w, att, eu, ws);
    k_edge<<<EB, ET, WCELLS * 4, stream>>>(ei, eattr, att, ws, E);
    k_reduce<<<(SLICE + 255) / 256, 256, 0, stream>>>(ws);
    k_out<<<NN, 128, 0, stream>>>(ws, eu, bias, (float*)d_out);
}

// Round 4
// 82.722 us; speedup vs baseline: 1.0695x; 1.0695x over previous
//
#include <hip/hip_runtime.h>

#define NN 177
#define NEG 0.2f
#define QR 45                 // dst rows per quarter (last quarter uses 42)
#define QSLOTS (QR * NN)      // 7965
#define SL 8064               // padded partial slice (QSLOTS + QR = 8010 -> 8064)
#define NCHUNK 128
#define EBLOCKS (NCHUNK * 4)  // 512
#define ETH 512

// workspace layout (floats)
#define AI_OFF   0
#define AJ_OFF   192
#define G_OFF    384
#define PART_OFF 23040        // 384 + 177*128 ; partials: 512 * SL floats (~16.5 MB)

// K1: h = x@weight (row in LDS); ai/aj attention dots; G = h@eu.
__global__ void k_node(const float* __restrict__ x, const float* __restrict__ w,
                       const float* __restrict__ att, const float* __restrict__ eu,
                       float* __restrict__ ws) {
    int n = blockIdx.x, c = threadIdx.x;
    __shared__ float xl[128], hl[128], r0[128], r1[128];
    xl[c] = x[n * 128 + c];
    __syncthreads();
    float acc = 0.f;
#pragma unroll 8
    for (int k = 0; k < 128; ++k) acc += xl[k] * w[k * 128 + c];
    hl[c] = acc;
    r0[c] = acc * att[c];
    r1[c] = acc * att[128 + c];
    __syncthreads();
    for (int off = 64; off > 0; off >>= 1) {
        if (c < off) { r0[c] += r0[c + off]; r1[c] += r1[c + off]; }
        __syncthreads();
    }
    if (c == 0) { ws[AI_OFF + n] = r0[0]; ws[AJ_OFF + n] = r1[0]; }
    __syncthreads();
    float acc2 = 0.f;
#pragma unroll 8
    for (int k = 0; k < 128; ++k) acc2 += hl[k] * eu[k * 128 + c];
    ws[G_OFF + n * 128 + c] = acc2;
}

// K2: edge pass. 2D grid: (chunk, dst-quarter). Private W-quarter in 32KB LDS,
// 4 blocks/CU * 8 waves = full occupancy, int4/float4 vectorized edge loads.
__global__ __launch_bounds__(ETH, 8)
void k_edge(const int* __restrict__ ei, const float* __restrict__ ea,
            const float* __restrict__ att, float* __restrict__ ws, int E, int CH) {
    int chunk = blockIdx.x >> 2, q = blockIdx.x & 3;
    int dlo = q * QR;
    int drows = NN - dlo; if (drows > QR) drows = QR;
    __shared__ float Wl[QSLOTS];
    __shared__ float ajl[NN], ailq[QR], Mq[QR], llast[QR];
    int tid = threadIdx.x;
    for (int i = tid; i < QSLOTS; i += ETH) Wl[i] = 0.f;
    for (int i = tid; i < NN; i += ETH) ajl[i] = ws[AJ_OFF + i];
    if (tid < QR) llast[tid] = 0.f;
    __syncthreads();
    // safe per-dst softmax shift (softmax is shift-invariant; bound only
    // prevents exp overflow): M_d = leaky(ai[d] + max_s aj[s] + 1.0)
    float ajmax = -1e30f;
    for (int i = 0; i < NN; ++i) ajmax = fmaxf(ajmax, ajl[i]);
    if (tid < drows) {
        float a = ws[AI_OFF + dlo + tid];
        ailq[tid] = a;
        float M = a + ajmax + 1.0f;
        Mq[tid] = (M > 0.f) ? M : NEG * M;
    }
    float cc = att[2 * 128];
    __syncthreads();

    const int base = chunk * CH;
    int lim = base + CH; if (lim > E) lim = E;
    const bool aligned4 = ((E & 3) == 0);
    for (int e0 = base + tid * 4; e0 < lim; e0 += ETH * 4) {
        int4 sv, dv; float4 eav;
        if (aligned4 && e0 + 3 < lim) {
            sv  = *(const int4*)(ei + e0);
            dv  = *(const int4*)(ei + E + e0);
            eav = *(const float4*)(ea + e0);
        } else {
            int e1 = (lim - e0 > 0) ? (lim - e0) : 0;
            sv.x = (e1 > 0) ? ei[e0]     : 0; dv.x = (e1 > 0) ? ei[E + e0]     : -1; eav.x = (e1 > 0) ? ea[e0]     : 0.f;
            sv.y = (e1 > 1) ? ei[e0 + 1] : 0; dv.y = (e1 > 1) ? ei[E + e0 + 1] : -1; eav.y = (e1 > 1) ? ea[e0 + 1] : 0.f;
            sv.z = (e1 > 2) ? ei[e0 + 2] : 0; dv.z = (e1 > 2) ? ei[E + e0 + 2] : -1; eav.z = (e1 > 2) ? ea[e0 + 2] : 0.f;
            sv.w = (e1 > 3) ? ei[e0 + 3] : 0; dv.w = (e1 > 3) ? ei[E + e0 + 3] : -1; eav.w = (e1 > 3) ? ea[e0 + 3] : 0.f;
        }
#define PROC(SS, DD, EE) do {                                   \
            int d_ = (DD) - dlo;                                \
            if ((unsigned)d_ < (unsigned)drows) {               \
                float t_ = ailq[d_] + ajl[SS] + cc * (EE);      \
                t_ = (t_ > 0.f) ? t_ : NEG * t_;                \
                float ev_ = __expf(t_ - Mq[d_]);                \
                atomicAdd(&Wl[d_ * NN + (SS)], ev_);            \
                atomicAdd(&llast[d_], ev_ * (EE));              \
            }                                                   \
        } while (0)
        PROC(sv.x, dv.x, eav.x);
        PROC(sv.y, dv.y, eav.y);
        PROC(sv.z, dv.z, eav.z);
        PROC(sv.w, dv.w, eav.w);
#undef PROC
    }
    __syncthreads();
    // coalesced flush of this block's partial slice
    float* part = ws + PART_OFF + (size_t)blockIdx.x * SL;
    for (int i = tid; i < QSLOTS; i += ETH) part[i] = Wl[i];
    if (tid < QR) part[QSLOTS + tid] = (tid < drows) ? llast[tid] : 0.f;
}

// K3: fused reduce + output. Block n: sum W-row n over its quarter's 128 chunk
// partials, then out[n][c] = (W[n,:]@G[:,c] + wlast[n]*eu[128,c]) / sum + bias[c].
__global__ void k_outred(const float* __restrict__ ws, const float* __restrict__ eu,
                         const float* __restrict__ bias, float* __restrict__ out) {
    int n = blockIdx.x, c = threadIdx.x;
    int q = n / QR, r = n % QR;
    __shared__ float wl[NN];
    __shared__ float red[128];
    const float* part = ws + PART_OFF + (size_t)q * SL;
    for (int s = c; s < NN; s += 128) {
        float acc = 0.f;
#pragma unroll 4
        for (int ch = 0; ch < NCHUNK; ++ch)
            acc += part[(size_t)ch * (4 * SL) + r * NN + s];
        wl[s] = acc;
    }
    // wlast: 128 threads <-> 128 chunks
    red[c] = part[(size_t)c * (4 * SL) + QSLOTS + r];
    __syncthreads();
    for (int off = 64; off > 0; off >>= 1) {
        if (c < off) red[c] += red[c + off];
        __syncthreads();
    }
    float wlast_n = red[0];
    __syncthreads();
    // row sum of W (softmax denominator)
    red[c] = wl[c] + ((c + 128 < NN) ? wl[c + 128] : 0.f);
    __syncthreads();
    for (int off = 64; off > 0; off >>= 1) {
        if (c < off) red[c] += red[c + off];
        __syncthreads();
    }
    float ssum = red[0];
    const float* G = ws + G_OFF;
    float acc = 0.f;
#pragma unroll 4
    for (int s = 0; s < NN; ++s) acc += wl[s] * G[s * 128 + c];
    out[n * 128 + c] = (acc + wlast_n * eu[128 * 128 + c]) / (ssum + 1e-16f) + bias[c];
}

extern "C" void kernel_launch(void* const* d_in, const int* in_sizes, int n_in,
                              void* d_out, int out_size, void* d_ws, size_t ws_size,
                              hipStream_t stream) {
    const float* x     = (const float*)d_in[0];
    const float* eattr = (const float*)d_in[1];
    const float* w     = (const float*)d_in[2];
    const float* att   = (const float*)d_in[3];
    const float* eu    = (const float*)d_in[4];
    const float* bias  = (const float*)d_in[5];
    const int*   ei    = (const int*)d_in[6];
    int E = in_sizes[6] / 2;
    int CH = (((E + NCHUNK - 1) / NCHUNK) + 3) & ~3;   // chunk size, multiple of 4
    float* ws = (float*)d_ws;

    k_node<<<NN, 128, 0, stream>>>(x, w, att, eu, ws);
    k_edge<<<EBLOCKS, ETH, 0, stream>>>(ei, eattr, att, ws, E, CH);
    k_outred<<<NN, 128, 0, stream>>>(ws, eu, bias, (float*)d_out);
}

// Round 5
// 62.469 us; speedup vs baseline: 1.4162x; 1.3242x over previous
//
#include <hip/hip_runtime.h>

#define NN 177
#define NEG 0.2f
#define QR 45                 // dst rows per quarter (last quarter uses 42)
#define QSLOTS (QR * NN)      // 7965
#define SL 8064               // padded partial slice (QSLOTS + QR -> 8064)
#define NCHUNK 128
#define EBLOCKS (NCHUNK * 4)  // 512
#define ETH 512
#define NGROUP 8              // stage-A reduction groups
#define CPG (NCHUNK / NGROUP) // 16 chunks per group

// workspace layout (floats)
#define AI_OFF   0
#define AJ_OFF   192
#define G_OFF    384
#define PART_OFF 23040                       // 512 slices of SL (~16.5 MB)
#define RED8_OFF (PART_OFF + EBLOCKS * SL)   // 8*4*SL floats (~1 MB)

// K1: h = x@weight; ai/aj attention dots; G = h@eu. 256 thr, split-K + 4 accs.
__global__ __launch_bounds__(256)
void k_node(const float* __restrict__ x, const float* __restrict__ w,
            const float* __restrict__ att, const float* __restrict__ eu,
            float* __restrict__ ws) {
    int n = blockIdx.x, tid = threadIdx.x;
    int c = tid & 127, half = tid >> 7;
    __shared__ float xl[128], hl[128], ph[256], r0[128], r1[128];
    if (tid < 128) xl[tid] = x[n * 128 + tid];
    __syncthreads();
    int k0 = half * 64;
    float a0 = 0.f, a1 = 0.f, a2 = 0.f, a3 = 0.f;
    const float* wp = w + (size_t)k0 * 128 + c;
#pragma unroll
    for (int k = 0; k < 64; k += 4) {
        a0 += xl[k0 + k]     * wp[(size_t)(k)     * 128];
        a1 += xl[k0 + k + 1] * wp[(size_t)(k + 1) * 128];
        a2 += xl[k0 + k + 2] * wp[(size_t)(k + 2) * 128];
        a3 += xl[k0 + k + 3] * wp[(size_t)(k + 3) * 128];
    }
    ph[tid] = (a0 + a1) + (a2 + a3);
    __syncthreads();
    if (half == 0) {
        float hv = ph[c] + ph[128 + c];
        hl[c] = hv;
        r0[c] = hv * att[c];
        r1[c] = hv * att[128 + c];
    }
    __syncthreads();
    for (int off = 64; off > 0; off >>= 1) {
        if (tid < off) { r0[tid] += r0[tid + off]; r1[tid] += r1[tid + off]; }
        __syncthreads();
    }
    if (tid == 0) { ws[AI_OFF + n] = r0[0]; ws[AJ_OFF + n] = r1[0]; }
    float b0 = 0.f, b1 = 0.f, b2 = 0.f, b3 = 0.f;
    const float* ep = eu + (size_t)k0 * 128 + c;
#pragma unroll
    for (int k = 0; k < 64; k += 4) {
        b0 += hl[k0 + k]     * ep[(size_t)(k)     * 128];
        b1 += hl[k0 + k + 1] * ep[(size_t)(k + 1) * 128];
        b2 += hl[k0 + k + 2] * ep[(size_t)(k + 2) * 128];
        b3 += hl[k0 + k + 3] * ep[(size_t)(k + 3) * 128];
    }
    ph[tid] = (b0 + b1) + (b2 + b3);
    __syncthreads();
    if (half == 0) ws[G_OFF + n * 128 + c] = ph[c] + ph[128 + c];
}

// K2: edge pass. 2D grid: (chunk, dst-quarter). Private W-quarter in 32KB LDS.
__global__ __launch_bounds__(ETH, 8)
void k_edge(const int* __restrict__ ei, const float* __restrict__ ea,
            const float* __restrict__ att, float* __restrict__ ws, int E, int CH) {
    int chunk = blockIdx.x >> 2, q = blockIdx.x & 3;
    int dlo = q * QR;
    int drows = NN - dlo; if (drows > QR) drows = QR;
    __shared__ float Wl[QSLOTS];
    __shared__ float ajl[NN], ailq[QR], Mq[QR], llast[QR];
    int tid = threadIdx.x;
    for (int i = tid; i < QSLOTS; i += ETH) Wl[i] = 0.f;
    for (int i = tid; i < NN; i += ETH) ajl[i] = ws[AJ_OFF + i];
    if (tid < QR) llast[tid] = 0.f;
    __syncthreads();
    // safe per-dst softmax shift (softmax is shift-invariant; bound prevents overflow)
    float ajmax = -1e30f;
    for (int i = 0; i < NN; ++i) ajmax = fmaxf(ajmax, ajl[i]);
    if (tid < drows) {
        float a = ws[AI_OFF + dlo + tid];
        ailq[tid] = a;
        float M = a + ajmax + 1.0f;
        Mq[tid] = (M > 0.f) ? M : NEG * M;
    }
    float cc = att[2 * 128];
    __syncthreads();

    const int base = chunk * CH;
    int lim = base + CH; if (lim > E) lim = E;
    const bool aligned4 = ((E & 3) == 0);
    for (int e0 = base + tid * 4; e0 < lim; e0 += ETH * 4) {
        int4 sv, dv; float4 eav;
        if (aligned4 && e0 + 3 < lim) {
            sv  = *(const int4*)(ei + e0);
            dv  = *(const int4*)(ei + E + e0);
            eav = *(const float4*)(ea + e0);
        } else {
            int e1 = (lim - e0 > 0) ? (lim - e0) : 0;
            sv.x = (e1 > 0) ? ei[e0]     : 0; dv.x = (e1 > 0) ? ei[E + e0]     : -1; eav.x = (e1 > 0) ? ea[e0]     : 0.f;
            sv.y = (e1 > 1) ? ei[e0 + 1] : 0; dv.y = (e1 > 1) ? ei[E + e0 + 1] : -1; eav.y = (e1 > 1) ? ea[e0 + 1] : 0.f;
            sv.z = (e1 > 2) ? ei[e0 + 2] : 0; dv.z = (e1 > 2) ? ei[E + e0 + 2] : -1; eav.z = (e1 > 2) ? ea[e0 + 2] : 0.f;
            sv.w = (e1 > 3) ? ei[e0 + 3] : 0; dv.w = (e1 > 3) ? ei[E + e0 + 3] : -1; eav.w = (e1 > 3) ? ea[e0 + 3] : 0.f;
        }
#define PROC(SS, DD, EE) do {                                   \
            int d_ = (DD) - dlo;                                \
            if ((unsigned)d_ < (unsigned)drows) {               \
                float t_ = ailq[d_] + ajl[SS] + cc * (EE);      \
                t_ = (t_ > 0.f) ? t_ : NEG * t_;                \
                float ev_ = __expf(t_ - Mq[d_]);                \
                atomicAdd(&Wl[d_ * NN + (SS)], ev_);            \
                atomicAdd(&llast[d_], ev_ * (EE));              \
            }                                                   \
        } while (0)
        PROC(sv.x, dv.x, eav.x);
        PROC(sv.y, dv.y, eav.y);
        PROC(sv.z, dv.z, eav.z);
        PROC(sv.w, dv.w, eav.w);
#undef PROC
    }
    __syncthreads();
    float* part = ws + PART_OFF + (size_t)blockIdx.x * SL;
    for (int i = tid; i < QSLOTS; i += ETH) part[i] = Wl[i];
    if (tid < QR) part[QSLOTS + tid] = (tid < drows) ? llast[tid] : 0.f;
}

// K3 stage A: reduce 128 chunks -> 8 groups. 258048 threads, 16 loads each.
__global__ void k_red8(float* __restrict__ ws) {
    int gid = blockIdx.x * 256 + threadIdx.x;   // < NGROUP*4*SL = 258048
    int g = gid / (4 * SL);
    int rem = gid - g * (4 * SL);
    const float* part = ws + PART_OFF;
    float acc = 0.f;
#pragma unroll
    for (int k = 0; k < CPG; ++k)
        acc += part[(size_t)(g * CPG + k) * (4 * SL) + rem];
    ws[RED8_OFF + gid] = acc;
}

// K3 stage B + output: sum 8 groups, then out = (W@G + wlast*eu_last)/rowsum + bias
__global__ void k_outred(const float* __restrict__ ws, const float* __restrict__ eu,
                         const float* __restrict__ bias, float* __restrict__ out) {
    int n = blockIdx.x, c = threadIdx.x;
    int q = n / QR, r = n % QR;
    __shared__ float wl[NN];
    __shared__ float red[128];
    const float* r8 = ws + RED8_OFF + (size_t)q * SL;
    for (int s = c; s < NN; s += 128) {
        float acc = 0.f;
#pragma unroll
        for (int g = 0; g < NGROUP; ++g)
            acc += r8[(size_t)g * (4 * SL) + r * NN + s];
        wl[s] = acc;
    }
    red[c] = (c < NGROUP) ? r8[(size_t)c * (4 * SL) + QSLOTS + r] : 0.f;
    __syncthreads();
    if (c < 4) red[c] += red[c + 4];
    __syncthreads();
    if (c < 2) red[c] += red[c + 2];
    __syncthreads();
    if (c == 0) red[0] += red[1];
    __syncthreads();
    float wlast_n = red[0];
    __syncthreads();
    red[c] = wl[c] + ((c + 128 < NN) ? wl[c + 128] : 0.f);
    __syncthreads();
    for (int off = 64; off > 0; off >>= 1) {
        if (c < off) red[c] += red[c + off];
        __syncthreads();
    }
    float ssum = red[0];
    const float* G = ws + G_OFF;
    float acc = 0.f;
#pragma unroll 4
    for (int s = 0; s < NN; ++s) acc += wl[s] * G[s * 128 + c];
    out[n * 128 + c] = (acc + wlast_n * eu[128 * 128 + c]) / (ssum + 1e-16f) + bias[c];
}

extern "C" void kernel_launch(void* const* d_in, const int* in_sizes, int n_in,
                              void* d_out, int out_size, void* d_ws, size_t ws_size,
                              hipStream_t stream) {
    const float* x     = (const float*)d_in[0];
    const float* eattr = (const float*)d_in[1];
    const float* w     = (const float*)d_in[2];
    const float* att   = (const float*)d_in[3];
    const float* eu    = (const float*)d_in[4];
    const float* bias  = (const float*)d_in[5];
    const int*   ei    = (const int*)d_in[6];
    int E = in_sizes[6] / 2;
    int CH = (((E + NCHUNK - 1) / NCHUNK) + 3) & ~3;   // chunk size, multiple of 4
    float* ws = (float*)d_ws;

    k_node<<<NN, 256, 0, stream>>>(x, w, att, eu, ws);
    k_edge<<<EBLOCKS, ETH, 0, stream>>>(ei, eattr, att, ws, E, CH);
    k_red8<<<(NGROUP * 4 * SL) / 256, 256, 0, stream>>>(ws);
    k_outred<<<NN, 128, 0, stream>>>(ws, eu, bias, (float*)d_out);
}